// Round 11
// baseline (690.194 us; speedup 1.0000x reference)
//
#include <hip/hip_runtime.h>
#include <math.h>

#define Bn   8
#define Cn   256
#define HWn  4096
#define FB   (Cn * HWn)      // 1048576 elems per batch-field
#define NTOT (Bn * FB)       // 8388608 elems per field
#define TEND 1.0
#define EPSK 1e-12f
#define NT   32              // apply N-tile (positions)
#define TPB  128             // tiles per batch
#define TSZ  8192            // elems per (b,tile): 256*32
#define RS   40              // staging row stride (shorts)
#define WTS  36              // wt / tred row stride (floats)

typedef float f32x4 __attribute__((ext_vector_type(4)));
typedef short bf16x8 __attribute__((ext_vector_type(8)));

__device__ inline float b2f(unsigned int u) {
    return __uint_as_float(u << 16);
}
__device__ inline unsigned short f2b(float f) {  // RNE
    unsigned u = __float_as_uint(f);
    unsigned r = u + 0x7FFFu + ((u >> 16) & 1u);
    return (unsigned short)(r >> 16);
}

// acc layout (floats, 8 batches each):
//   D[k][j] at acc[(k*8+j)*8 + b];  Nsq[j] at acc[512 + j*8 + b];  coords at acc+576

__global__ void init_kernel(float* __restrict__ p) {
    for (int i = threadIdx.x; i < 1024; i += 256) p[i] = 0.0f;
}

// ---- split W into bf16 hi/lo in MFMA-A staged layout ----
__global__ void wsplit_kernel(const float* __restrict__ W,
                              unsigned short* __restrict__ Whs,
                              unsigned short* __restrict__ Wls) {
    int kc = blockIdx.x, mt = blockIdx.y, l = threadIdx.x;
    int m = mt * 16 + (l & 15);
    int k0 = kc * 32 + (l >> 4) * 8;
#pragma unroll
    for (int j = 0; j < 8; ++j) {
        float wv = W[m * 256 + k0 + j];
        unsigned short h = f2b(wv);
        unsigned short lo = f2b(wv - b2f(h));
        int idx = ((kc * 16 + mt) * 64 + l) * 8 + j;
        Whs[idx] = h; Wls[idx] = lo;
    }
}

// ================= fused Krylov step (K=-1: Z build; K=0..7: step) =============
// Grid (128,8) = 1024 blocks = 4 blocks/CU (the r5 lever: 4 independent barrier
// domains per CU keep load streams alive; no duplication, no cross-block race).
// NT=32 + TILE-MAJOR w/Q/Z [b][tile][c][32] -> each block's regions contiguous
// (kills r3's 64B line-split). s0/v standard layout (32-pos = one 128B line).
// 256 threads, __launch_bounds__(256,4): cap 128 VGPR (session rule: arg2 acts
// as blocks/CU on this toolchain; (512,4) -> 64-cap spill disaster, r6/r8).
// Per chunk (async split): issue loads(kc+1) -> MFMA(kc) -> consume(kc+1).
//   K>=0: x = w - sum cj*basis (CGS) -> Q_{K-1} bf16; P = s0*xr hi/lo -> LDS;
//         ac += W@P. Epilogue: w' = ac - Z*t (Z field bf16 hi/lo, r4 numerics),
//         t = colsum(s0*xr); coalesced tile-major write + dots D[K][j].
//   K=-1: P = s0; epilogue writes Zh/Zl.
template <int K>
__global__ __launch_bounds__(256, 4) void step_kernel(
        const float* __restrict__ v, const float* __restrict__ s0,
        const unsigned short* __restrict__ Whs, const unsigned short* __restrict__ Wls,
        unsigned short* __restrict__ Qb, float* __restrict__ acc,
        float* __restrict__ w,
        unsigned short* __restrict__ Zh, unsigned short* __restrict__ Zl) {
    __shared__ __align__(16) char smem_u[36864];
    short* Ph0 = (short*)smem_u;                  // 32*RS*2 = 2560 B each
    short* Ph1 = (short*)(smem_u + 2560);
    short* Pl0 = (short*)(smem_u + 5120);
    short* Pl1 = (short*)(smem_u + 7680);
    float* tredf = (float*)(smem_u + 10240);      // 32*WTS*4 = 4608 B
    float* wt    = (float*)smem_u;                // 256*WTS*4 = 36864 B (epilogue)
    __shared__ float ts[NT];
    __shared__ float nred[4];
    __shared__ float dred[4][8];

    const int tid = threadIdx.x;
    const int lane = tid & 63, wvi = tid >> 6;
    const int b = blockIdx.y;
    const int tIdx = blockIdx.x;
    const int sbase = tIdx * NT;
    const size_t boff = (size_t)b * FB;
    const size_t tb = ((size_t)b * TPB + tIdx) * TSZ;
    const int mbase = wvi * 64;        // 64 output rows per wave
    const int cch = tid >> 3;          // 0..31: channel within chunk
    const int pos4 = (tid & 7) * 4;    // 0..28
    const int codd = cch & 1;
    const int c2s = cch >> 1;          // 0..15: 4-byte slot index

    // ---- CGS coefficients from previous step's dots ----
    float cj[K > 0 ? K : 1];
    if (K > 0) {
        float mm[K > 0 ? K : 1];
        mm[0] = sqrtf(acc[512 + b]);
#pragma unroll
        for (int j = 1; j < K; ++j) mm[j] = sqrtf(acc[512 + j * 8 + b]) + EPSK * mm[j - 1];
#pragma unroll
        for (int j = 0; j < K; ++j)
            cj[j] = acc[((K - 1) * 8 + j) * 8 + b] / (mm[j] * mm[j]);
    }
    unsigned short* QK = Qb + (size_t)(K > 0 ? K - 1 : 0) * NTOT;

    float tp[4] = {0.f, 0.f, 0.f, 0.f};
    float np = 0.f;

    // paired-write: partner channel is cch^1 -> lane tid^8. XOR-swizzled slot.
    auto wr2 = [&](short* buf, unsigned x01, unsigned x23) {
        unsigned p01 = (unsigned)__shfl_xor((int)x01, 8);
        unsigned p23 = (unsigned)__shfl_xor((int)x23, 8);
        unsigned mine = codd ? x23 : x01;
        unsigned theirs = codd ? p23 : p01;
        unsigned w0, w1;
        if (codd) {
            w0 = (theirs & 0xFFFFu) | (mine << 16);
            w1 = (theirs >> 16) | (mine & 0xFFFF0000u);
        } else {
            w0 = (mine & 0xFFFFu) | (theirs << 16);
            w1 = (mine >> 16) | (theirs & 0xFFFF0000u);
        }
        int P0 = pos4 + 2 * codd;
        int slot = c2s ^ (((P0 >> 3) & 3) << 2);
        *(unsigned*)(buf + P0 * RS + slot * 2) = w0;
        *(unsigned*)(buf + (P0 + 1) * RS + slot * 2) = w1;
    };

    struct Ld {
        float4 s4, w4, v4;
        ushort4 q[K > 1 ? K - 1 : 1];
    };
    auto issue = [&](int kc) -> Ld {
        Ld L;
        const size_t os = boff + (size_t)(kc * 32 + cch) * HWn + sbase + pos4;  // std
        const size_t ot = tb + (size_t)((kc * 32 + cch) * NT + pos4);           // tile-major
        L.s4 = *(const float4*)(s0 + os);
        if (K == 0) {
            L.v4 = *(const float4*)(v + os);
        } else if (K > 0) {
            L.w4 = *(const float4*)(w + ot);
            L.v4 = *(const float4*)(v + os);
#pragma unroll
            for (int j = 1; j < K; ++j)
                L.q[j - 1] = *(const ushort4*)(Qb + (size_t)(j - 1) * NTOT + ot);
        }
        return L;
    };
    auto consume = [&](Ld& L, int kc, int bb) {
        const size_t ot = tb + (size_t)((kc * 32 + cch) * NT + pos4);
        float se[4] = {L.s4.x, L.s4.y, L.s4.z, L.s4.w};
        float xr[4] = {0.f, 0.f, 0.f, 0.f};
        if (K == 0) {
            xr[0] = L.v4.x; xr[1] = L.v4.y; xr[2] = L.v4.z; xr[3] = L.v4.w;
        } else if (K > 0) {
            float xe[4];
            xe[0] = fmaf(-cj[0], L.v4.x, L.w4.x);
            xe[1] = fmaf(-cj[0], L.v4.y, L.w4.y);
            xe[2] = fmaf(-cj[0], L.v4.z, L.w4.z);
            xe[3] = fmaf(-cj[0], L.v4.w, L.w4.w);
#pragma unroll
            for (int j = 1; j < K; ++j) {
                xe[0] = fmaf(-cj[j], b2f(L.q[j - 1].x), xe[0]);
                xe[1] = fmaf(-cj[j], b2f(L.q[j - 1].y), xe[1]);
                xe[2] = fmaf(-cj[j], b2f(L.q[j - 1].z), xe[2]);
                xe[3] = fmaf(-cj[j], b2f(L.q[j - 1].w), xe[3]);
            }
            unsigned h0 = f2b(xe[0]), h1 = f2b(xe[1]);
            unsigned h2 = f2b(xe[2]), h3 = f2b(xe[3]);
            ushort4 o;
            o.x = (unsigned short)h0; o.y = (unsigned short)h1;
            o.z = (unsigned short)h2; o.w = (unsigned short)h3;
            *(ushort4*)(QK + ot) = o;
            xr[0] = b2f(h0); xr[1] = b2f(h1); xr[2] = b2f(h2); xr[3] = b2f(h3);
        }
        unsigned phx[4], plx[4];
#pragma unroll
        for (int i = 0; i < 4; ++i) {
            float pe;
            if (K < 0) {
                pe = se[i];
            } else {
                np = fmaf(xr[i], xr[i], np);
                tp[i] = fmaf(xr[i], se[i], tp[i]);
                pe = se[i] * xr[i];
            }
            unsigned hp = f2b(pe);
            phx[i] = hp; plx[i] = f2b(pe - b2f((unsigned short)hp));
        }
        wr2(bb ? Ph1 : Ph0, phx[0] | (phx[1] << 16), phx[2] | (phx[3] << 16));
        wr2(bb ? Pl1 : Pl0, plx[0] | (plx[1] << 16), plx[2] | (plx[3] << 16));
    };

    f32x4 ac[4][2];
#pragma unroll
    for (int i = 0; i < 4; ++i)
#pragma unroll
        for (int j = 0; j < 2; ++j) ac[i][j] = (f32x4){0.f, 0.f, 0.f, 0.f};

    const int r15 = lane & 15, qq = lane >> 4;
    {   // prologue
        Ld L0 = issue(0);
        consume(L0, 0, 0);
    }
    for (int kc = 0; kc < 8; ++kc) {
        __syncthreads();               // buf[kc&1] staged; buf[kc^1] reads done
        bf16x8 ah[4], al[4];
#pragma unroll
        for (int rt = 0; rt < 4; ++rt) {
            int mt = wvi * 4 + rt;
            ah[rt] = *(const bf16x8*)(Whs + (size_t)kc * 8192 + (mt * 64 + lane) * 8);
            al[rt] = *(const bf16x8*)(Wls + (size_t)kc * 8192 + (mt * 64 + lane) * 8);
        }
        Ld Ln;
        if (kc < 7) Ln = issue(kc + 1);   // fire next-chunk loads, no wait
        const short* ph = (kc & 1) ? Ph1 : Ph0;
        const short* pl = (kc & 1) ? Pl1 : Pl0;
#pragma unroll
        for (int ct = 0; ct < 2; ++ct) {
            int n = ct * 16 + r15;
            int grp = qq ^ ((n >> 3) & 3);
            int off = n * RS + grp * 8;
            bf16x8 bh = *(const bf16x8*)(ph + off);
            bf16x8 bl = *(const bf16x8*)(pl + off);
#pragma unroll
            for (int rt = 0; rt < 4; ++rt) {
                ac[rt][ct] = __builtin_amdgcn_mfma_f32_16x16x32_bf16(ah[rt], bh, ac[rt][ct], 0, 0, 0);
                ac[rt][ct] = __builtin_amdgcn_mfma_f32_16x16x32_bf16(ah[rt], bl, ac[rt][ct], 0, 0, 0);
                ac[rt][ct] = __builtin_amdgcn_mfma_f32_16x16x32_bf16(al[rt], bh, ac[rt][ct], 0, 0, 0);
            }
        }
        if (kc < 7) consume(Ln, kc + 1, (kc + 1) & 1);  // vmcnt wait lands HERE
    }

    // ---- t / norm reductions ----
    __syncthreads();
    if (K >= 0) {
        *(float4*)(tredf + cch * WTS + pos4) = *(float4*)tp;
        float q2 = np;
        for (int off2 = 32; off2 > 0; off2 >>= 1) q2 += __shfl_down(q2, off2);
        if (lane == 0) nred[wvi] = q2;
    }
    __syncthreads();
    if (K >= 0) {
        if (tid < NT) {
            float s = 0.f;
#pragma unroll
            for (int g = 0; g < 32; ++g) s += tredf[g * WTS + tid];
            ts[tid] = s;
        }
        if (tid == 0)
            atomicAdd(&acc[512 + K * 8 + b], nred[0] + nred[1] + nred[2] + nred[3]);
    }
    __syncthreads();   // ts ready; tred reads done (wt aliases everything)

    // ---- transpose acc into wt ----
#pragma unroll
    for (int rt = 0; rt < 4; ++rt)
#pragma unroll
        for (int ct = 0; ct < 2; ++ct) {
            int col = ct * 16 + r15;
            int r0 = mbase + rt * 16 + qq * 4;
#pragma unroll
            for (int reg = 0; reg < 4; ++reg)
                wt[(r0 + reg) * WTS + col] = ac[rt][ct][reg];
        }
    __syncthreads();

    // ---- coalesced epilogue: K<0 write Z; K>=0 w' = wt - Z*t, write + dots ----
    float dp[K >= 0 ? K + 1 : 1];
#pragma unroll
    for (int j = 0; j < (K >= 0 ? K + 1 : 1); ++j) dp[j] = 0.f;
#pragma unroll
    for (int rr = 0; rr < 8; ++rr) {
        int row = rr * 32 + (tid >> 3);
        int col = (tid & 7) * 4;
        float4 wv4 = *(const float4*)(wt + row * WTS + col);
        size_t it = tb + (size_t)(row * NT + col);                 // tile-major
        if (K < 0) {
            ushort4 zh4, zl4;
            unsigned short h0 = f2b(wv4.x), h1 = f2b(wv4.y);
            unsigned short h2 = f2b(wv4.z), h3 = f2b(wv4.w);
            zh4.x = h0; zh4.y = h1; zh4.z = h2; zh4.w = h3;
            zl4.x = f2b(wv4.x - b2f(h0)); zl4.y = f2b(wv4.y - b2f(h1));
            zl4.z = f2b(wv4.z - b2f(h2)); zl4.w = f2b(wv4.w - b2f(h3));
            *(ushort4*)(Zh + it) = zh4;
            *(ushort4*)(Zl + it) = zl4;
        } else {
            size_t is = boff + (size_t)row * HWn + sbase + col;    // std (v)
            ushort4 zh4 = *(const ushort4*)(Zh + it);
            ushort4 zl4 = *(const ushort4*)(Zl + it);
            float z0 = b2f(zh4.x) + b2f(zl4.x), z1 = b2f(zh4.y) + b2f(zl4.y);
            float z2 = b2f(zh4.z) + b2f(zl4.z), z3 = b2f(zh4.w) + b2f(zl4.w);
            float4 wf;
            wf.x = wv4.x - z0 * ts[col + 0];
            wf.y = wv4.y - z1 * ts[col + 1];
            wf.z = wv4.z - z2 * ts[col + 2];
            wf.w = wv4.w - z3 * ts[col + 3];
            *(float4*)(w + it) = wf;
            float4 vv4 = *(const float4*)(v + is);
            dp[0] = fmaf(wf.x, vv4.x, dp[0]);
            dp[0] = fmaf(wf.y, vv4.y, dp[0]);
            dp[0] = fmaf(wf.z, vv4.z, dp[0]);
            dp[0] = fmaf(wf.w, vv4.w, dp[0]);
#pragma unroll
            for (int j = 1; j <= (K >= 0 ? K : 0); ++j) {
                ushort4 u = *(const ushort4*)(Qb + (size_t)(j - 1) * NTOT + it);
                dp[j] = fmaf(wf.x, b2f(u.x), dp[j]);
                dp[j] = fmaf(wf.y, b2f(u.y), dp[j]);
                dp[j] = fmaf(wf.z, b2f(u.z), dp[j]);
                dp[j] = fmaf(wf.w, b2f(u.w), dp[j]);
            }
        }
    }
    if (K >= 0) {
#pragma unroll
        for (int j = 0; j <= K; ++j) {
            float q2 = dp[j];
            for (int off2 = 32; off2 > 0; off2 >>= 1) q2 += __shfl_down(q2, off2);
            if (lane == 0) dred[wvi][j] = q2;
        }
        __syncthreads();
        if (tid <= K)
            atomicAdd(&acc[(K * 8 + tid) * 8 + b],
                      dred[0][tid] + dred[1][tid] + dred[2][tid] + dred[3][tid]);
    }
}

// ---------------- expm of 9x9 per batch (fp64); emits combine coeffs ----------
__global__ __launch_bounds__(128) void expm_kernel(const float* __restrict__ acc,
                                                   float* __restrict__ coordsOut) {
    __shared__ double Am[81], Pm[81], Tm[81];
    __shared__ double ssc;
    __shared__ int sn;
    const int b = blockIdx.x;
    const int t = threadIdx.x;
    const int r = t / 9, c = t % 9;
    double m[8];
    m[0] = sqrt((double)acc[512 + b]);
    for (int j = 1; j < 8; ++j) m[j] = sqrt((double)acc[512 + j * 8 + b]) + 1e-12 * m[j - 1];
    if (t < 81) {
        double val = 0.0;
        if (r < 8 && c < 8) {
            if (r <= c) val = TEND * (double)acc[(c * 8 + r) * 8 + b] / (m[r] * m[c]);
            else if (r == c + 1) val = TEND * sqrt((double)acc[512 + r * 8 + b]) / m[c];
        }
        if (r == 0 && c == 8) val = TEND;
        Am[t] = val;
    }
    __syncthreads();
    if (t == 0) {
        double mx = 0.0;
        for (int rr = 0; rr < 9; ++rr) {
            double s = 0.0;
            for (int cc = 0; cc < 9; ++cc) s += fabs(Am[rr * 9 + cc]);
            if (s > mx) mx = s;
        }
        int n = 0;
        while (mx > 0.25 && n < 48) { mx *= 0.5; ++n; }
        double sc = 1.0;
        for (int ii = 0; ii < n; ++ii) sc *= 0.5;
        sn = n; ssc = sc;
    }
    __syncthreads();
    if (t < 81) Am[t] *= ssc;
    __syncthreads();
    if (t < 81) Pm[t] = (r == c) ? 1.0 : 0.0;
    __syncthreads();
    for (int i = 20; i >= 1; --i) {
        if (t < 81) {
            double s = 0.0;
            for (int k = 0; k < 9; ++k) s += Am[r * 9 + k] * Pm[k * 9 + c];
            Tm[t] = ((r == c) ? 1.0 : 0.0) + s / (double)i;
        }
        __syncthreads();
        if (t < 81) Pm[t] = Tm[t];
        __syncthreads();
    }
    int n = sn;
    for (int q = 0; q < n; ++q) {
        if (t < 81) {
            double s = 0.0;
            for (int k = 0; k < 9; ++k) s += Pm[r * 9 + k] * Pm[k * 9 + c];
            Tm[t] = s;
        }
        __syncthreads();
        if (t < 81) Pm[t] = Tm[t];
        __syncthreads();
    }
    if (t < 8) coordsOut[b * 8 + t] = (float)(Pm[t * 9 + 8] * m[0] / m[t]);
}

// ------ out = coeff_0*v + sum_{j=1..7} coeff_j * U_j (tile-major bf16 Q) ------
__global__ __launch_bounds__(256) void combine_kernel(const unsigned short* __restrict__ Qb,
                                                      const float* __restrict__ v,
                                                      const float* __restrict__ coords,
                                                      float* __restrict__ out) {
    int t = blockIdx.x, b = blockIdx.y;
    const size_t boff = (size_t)b * FB;
    const size_t tb = ((size_t)b * TPB + t) * TSZ;
    float cf[8];
#pragma unroll
    for (int j = 0; j < 8; ++j) cf[j] = coords[b * 8 + j];
    int rg = threadIdx.x >> 3;
    int pos4 = (threadIdx.x & 7) * 4;
#pragma unroll
    for (int ri = 0; ri < 8; ++ri) {
        int r = ri * 32 + rg;
        size_t it = tb + (size_t)(r * NT + pos4);
        size_t is = boff + (size_t)r * HWn + t * NT + pos4;
        float4 vv = *(const float4*)(v + is);
        float a[4] = {cf[0] * vv.x, cf[0] * vv.y, cf[0] * vv.z, cf[0] * vv.w};
#pragma unroll
        for (int j = 1; j < 8; ++j) {
            ushort4 u = *(const ushort4*)(Qb + (size_t)(j - 1) * NTOT + it);
            a[0] = fmaf(cf[j], b2f(u.x), a[0]);
            a[1] = fmaf(cf[j], b2f(u.y), a[1]);
            a[2] = fmaf(cf[j], b2f(u.z), a[2]);
            a[3] = fmaf(cf[j], b2f(u.w), a[3]);
        }
        float4 o = {a[0], a[1], a[2], a[3]};
        *(float4*)(out + is) = o;
    }
}

extern "C" void kernel_launch(void* const* d_in, const int* in_sizes, int n_in,
                              void* d_out, int out_size, void* d_ws, size_t ws_size,
                              hipStream_t stream) {
    const float* s0 = (const float*)d_in[0];
    const float* v  = (const float*)d_in[1];
    const float* W  = (const float*)d_in[2];
    float* out = (float*)d_out;

    // ws (floats): [acc 576 | coords 64 | pad->1024 | Whs 32768 | Wls 32768 |
    //               Zh bf16 NTOT | Zl bf16 NTOT | Qb bf16 7*NTOT]  (r4 footprint)
    float* ws     = (float*)d_ws;
    float* acc    = ws;
    float* coords = ws + 576;
    unsigned short* Whs = (unsigned short*)(ws + 1024);
    unsigned short* Wls = Whs + 65536;
    unsigned short* Zh  = (unsigned short*)(ws + 1024 + 65536);
    unsigned short* Zl  = Zh + NTOT;
    unsigned short* Qb  = Zh + 2 * (size_t)NTOT;   // 7 bf16 fields, tile-major
    float* w      = out;   // working A-output (fp32, tile-major during steps)

    init_kernel<<<dim3(1), dim3(256), 0, stream>>>(ws);
    wsplit_kernel<<<dim3(8, 16), dim3(64), 0, stream>>>(W, Whs, Wls);

    dim3 ga(TPB, 8), blk(256);
    // Z = W @ s0 (once, bf16 hi/lo, tile-major)
    step_kernel<-1><<<ga, blk, 0, stream>>>(v, s0, Whs, Wls, Qb, acc, w, Zh, Zl);
#define STEPK(K) step_kernel<K><<<ga, blk, 0, stream>>>(v, s0, Whs, Wls, Qb, acc, w, Zh, Zl);
    STEPK(0) STEPK(1) STEPK(2) STEPK(3) STEPK(4) STEPK(5) STEPK(6) STEPK(7)
#undef STEPK

    expm_kernel<<<dim3(8), dim3(128), 0, stream>>>(acc, coords);
    combine_kernel<<<dim3(TPB, 8), blk, 0, stream>>>(Qb, v, coords, out);
}

// Round 12
// 511.846 us; speedup vs baseline: 1.3484x; 1.3484x over previous
//
#include <hip/hip_runtime.h>
#include <math.h>

#define Bn   8
#define Cn   256
#define HWn  4096
#define FB   (Cn * HWn)      // 1048576 elems per batch-field
#define NTOT (Bn * FB)       // 8388608 elems per field
#define TEND 1.0
#define EPSK 1e-12f
#define NT   32              // apply N-tile (positions)
#define TPB  128             // tiles per batch
#define TSZ  8192            // elems per (b,tile): 256*32
#define RS   40              // staging row stride (shorts)
#define WTS  36              // wt / tred row stride (floats)

typedef float f32x4 __attribute__((ext_vector_type(4)));
typedef short bf16x8 __attribute__((ext_vector_type(8)));

__device__ inline float b2f(unsigned int u) {
    return __uint_as_float(u << 16);
}
__device__ inline unsigned short f2b(float f) {  // RNE
    unsigned u = __float_as_uint(f);
    unsigned r = u + 0x7FFFu + ((u >> 16) & 1u);
    return (unsigned short)(r >> 16);
}

// acc layout (floats, 8 batches each):
//   D[k][j] at acc[(k*8+j)*8 + b];  Nsq[j] at acc[512 + j*8 + b];  coords at acc+576

__global__ void init_kernel(float* __restrict__ p) {
    for (int i = threadIdx.x; i < 1024; i += 256) p[i] = 0.0f;
}

// ---- split W into bf16 hi/lo in MFMA-A staged layout ----
__global__ void wsplit_kernel(const float* __restrict__ W,
                              unsigned short* __restrict__ Whs,
                              unsigned short* __restrict__ Wls) {
    int kc = blockIdx.x, mt = blockIdx.y, l = threadIdx.x;
    int m = mt * 16 + (l & 15);
    int k0 = kc * 32 + (l >> 4) * 8;
#pragma unroll
    for (int j = 0; j < 8; ++j) {
        float wv = W[m * 256 + k0 + j];
        unsigned short h = f2b(wv);
        unsigned short lo = f2b(wv - b2f(h));
        int idx = ((kc * 16 + mt) * 64 + l) * 8 + j;
        Whs[idx] = h; Wls[idx] = lo;
    }
}

// ================= fused Krylov step (K=-1: Z build; K=0..7: step) =============
// Grid (128,8) = 1024 blocks = 4 blocks/CU (4 independent barrier domains/CU —
// r11 proved this reaches 3.25 TB/s even WITH spill). NT=32 + TILE-MAJOR w/Q/Z
// [b][tile][c][32]; s0/v standard layout (32-pos = one aligned 128B line).
// TOOLCHAIN RULE (r2/r4-r11 collated): VGPR cap = 256/arg2 of __launch_bounds__
// (arg2=4 -> 64-cap -> spill disaster r6/r8/r11; arg2=2 -> 128-cap).
// (256,2): cap 128; body needs ~110 -> no spill; runtime occupancy from real
// resources: LDS 37.4KB -> 4 blocks/CU, VGPR<=128 -> 4 waves/SIMD.
// Per chunk (async split): issue loads(kc+1) -> MFMA(kc) -> consume(kc+1).
//   K>=0: x = w - sum cj*basis (CGS) -> Q_{K-1} bf16; P = s0*xr hi/lo -> LDS;
//         ac += W@P. Epilogue: w' = ac - Z*t (Z field bf16 hi/lo, r4 numerics),
//         t = colsum(s0*xr); coalesced tile-major write + dots D[K][j].
//   K=-1: P = s0; epilogue writes Zh/Zl.
template <int K>
__global__ __launch_bounds__(256, 2) void step_kernel(
        const float* __restrict__ v, const float* __restrict__ s0,
        const unsigned short* __restrict__ Whs, const unsigned short* __restrict__ Wls,
        unsigned short* __restrict__ Qb, float* __restrict__ acc,
        float* __restrict__ w,
        unsigned short* __restrict__ Zh, unsigned short* __restrict__ Zl) {
    __shared__ __align__(16) char smem_u[36864];
    short* Ph0 = (short*)smem_u;                  // 32*RS*2 = 2560 B each
    short* Ph1 = (short*)(smem_u + 2560);
    short* Pl0 = (short*)(smem_u + 5120);
    short* Pl1 = (short*)(smem_u + 7680);
    float* tredf = (float*)(smem_u + 10240);      // 32*WTS*4 = 4608 B
    float* wt    = (float*)smem_u;                // 256*WTS*4 = 36864 B (epilogue)
    __shared__ float ts[NT];
    __shared__ float nred[4];
    __shared__ float dred[4][8];

    const int tid = threadIdx.x;
    const int lane = tid & 63, wvi = tid >> 6;
    const int b = blockIdx.y;
    const int tIdx = blockIdx.x;
    const int sbase = tIdx * NT;
    const size_t boff = (size_t)b * FB;
    const size_t tb = ((size_t)b * TPB + tIdx) * TSZ;
    const int mbase = wvi * 64;        // 64 output rows per wave
    const int cch = tid >> 3;          // 0..31: channel within chunk
    const int pos4 = (tid & 7) * 4;    // 0..28
    const int codd = cch & 1;
    const int c2s = cch >> 1;          // 0..15: 4-byte slot index

    // ---- CGS coefficients from previous step's dots ----
    float cj[K > 0 ? K : 1];
    if (K > 0) {
        float mm[K > 0 ? K : 1];
        mm[0] = sqrtf(acc[512 + b]);
#pragma unroll
        for (int j = 1; j < K; ++j) mm[j] = sqrtf(acc[512 + j * 8 + b]) + EPSK * mm[j - 1];
#pragma unroll
        for (int j = 0; j < K; ++j)
            cj[j] = acc[((K - 1) * 8 + j) * 8 + b] / (mm[j] * mm[j]);
    }
    unsigned short* QK = Qb + (size_t)(K > 0 ? K - 1 : 0) * NTOT;

    float tp[4] = {0.f, 0.f, 0.f, 0.f};
    float np = 0.f;

    // paired-write: partner channel is cch^1 -> lane tid^8. XOR-swizzled slot.
    auto wr2 = [&](short* buf, unsigned x01, unsigned x23) {
        unsigned p01 = (unsigned)__shfl_xor((int)x01, 8);
        unsigned p23 = (unsigned)__shfl_xor((int)x23, 8);
        unsigned mine = codd ? x23 : x01;
        unsigned theirs = codd ? p23 : p01;
        unsigned w0, w1;
        if (codd) {
            w0 = (theirs & 0xFFFFu) | (mine << 16);
            w1 = (theirs >> 16) | (mine & 0xFFFF0000u);
        } else {
            w0 = (mine & 0xFFFFu) | (theirs << 16);
            w1 = (mine >> 16) | (theirs & 0xFFFF0000u);
        }
        int P0 = pos4 + 2 * codd;
        int slot = c2s ^ (((P0 >> 3) & 3) << 2);
        *(unsigned*)(buf + P0 * RS + slot * 2) = w0;
        *(unsigned*)(buf + (P0 + 1) * RS + slot * 2) = w1;
    };

    struct Ld {
        float4 s4, w4, v4;
        ushort4 q[K > 1 ? K - 1 : 1];
    };
    auto issue = [&](int kc) -> Ld {
        Ld L;
        const size_t os = boff + (size_t)(kc * 32 + cch) * HWn + sbase + pos4;  // std
        const size_t ot = tb + (size_t)((kc * 32 + cch) * NT + pos4);           // tile-major
        L.s4 = *(const float4*)(s0 + os);
        if (K == 0) {
            L.v4 = *(const float4*)(v + os);
        } else if (K > 0) {
            L.w4 = *(const float4*)(w + ot);
            L.v4 = *(const float4*)(v + os);
#pragma unroll
            for (int j = 1; j < K; ++j)
                L.q[j - 1] = *(const ushort4*)(Qb + (size_t)(j - 1) * NTOT + ot);
        }
        return L;
    };
    auto consume = [&](Ld& L, int kc, int bb) {
        const size_t ot = tb + (size_t)((kc * 32 + cch) * NT + pos4);
        float se[4] = {L.s4.x, L.s4.y, L.s4.z, L.s4.w};
        float xr[4] = {0.f, 0.f, 0.f, 0.f};
        if (K == 0) {
            xr[0] = L.v4.x; xr[1] = L.v4.y; xr[2] = L.v4.z; xr[3] = L.v4.w;
        } else if (K > 0) {
            float xe[4];
            xe[0] = fmaf(-cj[0], L.v4.x, L.w4.x);
            xe[1] = fmaf(-cj[0], L.v4.y, L.w4.y);
            xe[2] = fmaf(-cj[0], L.v4.z, L.w4.z);
            xe[3] = fmaf(-cj[0], L.v4.w, L.w4.w);
#pragma unroll
            for (int j = 1; j < K; ++j) {
                xe[0] = fmaf(-cj[j], b2f(L.q[j - 1].x), xe[0]);
                xe[1] = fmaf(-cj[j], b2f(L.q[j - 1].y), xe[1]);
                xe[2] = fmaf(-cj[j], b2f(L.q[j - 1].z), xe[2]);
                xe[3] = fmaf(-cj[j], b2f(L.q[j - 1].w), xe[3]);
            }
            unsigned h0 = f2b(xe[0]), h1 = f2b(xe[1]);
            unsigned h2 = f2b(xe[2]), h3 = f2b(xe[3]);
            ushort4 o;
            o.x = (unsigned short)h0; o.y = (unsigned short)h1;
            o.z = (unsigned short)h2; o.w = (unsigned short)h3;
            *(ushort4*)(QK + ot) = o;
            xr[0] = b2f(h0); xr[1] = b2f(h1); xr[2] = b2f(h2); xr[3] = b2f(h3);
        }
        unsigned phx[4], plx[4];
#pragma unroll
        for (int i = 0; i < 4; ++i) {
            float pe;
            if (K < 0) {
                pe = se[i];
            } else {
                np = fmaf(xr[i], xr[i], np);
                tp[i] = fmaf(xr[i], se[i], tp[i]);
                pe = se[i] * xr[i];
            }
            unsigned hp = f2b(pe);
            phx[i] = hp; plx[i] = f2b(pe - b2f((unsigned short)hp));
        }
        wr2(bb ? Ph1 : Ph0, phx[0] | (phx[1] << 16), phx[2] | (phx[3] << 16));
        wr2(bb ? Pl1 : Pl0, plx[0] | (plx[1] << 16), plx[2] | (plx[3] << 16));
    };

    f32x4 ac[4][2];
#pragma unroll
    for (int i = 0; i < 4; ++i)
#pragma unroll
        for (int j = 0; j < 2; ++j) ac[i][j] = (f32x4){0.f, 0.f, 0.f, 0.f};

    const int r15 = lane & 15, qq = lane >> 4;
    {   // prologue
        Ld L0 = issue(0);
        consume(L0, 0, 0);
    }
    for (int kc = 0; kc < 8; ++kc) {
        __syncthreads();               // buf[kc&1] staged; buf[kc^1] reads done
        bf16x8 ah[4], al[4];
#pragma unroll
        for (int rt = 0; rt < 4; ++rt) {
            int mt = wvi * 4 + rt;
            ah[rt] = *(const bf16x8*)(Whs + (size_t)kc * 8192 + (mt * 64 + lane) * 8);
            al[rt] = *(const bf16x8*)(Wls + (size_t)kc * 8192 + (mt * 64 + lane) * 8);
        }
        Ld Ln;
        if (kc < 7) Ln = issue(kc + 1);   // fire next-chunk loads, no wait
        const short* ph = (kc & 1) ? Ph1 : Ph0;
        const short* pl = (kc & 1) ? Pl1 : Pl0;
#pragma unroll
        for (int ct = 0; ct < 2; ++ct) {
            int n = ct * 16 + r15;
            int grp = qq ^ ((n >> 3) & 3);
            int off = n * RS + grp * 8;
            bf16x8 bh = *(const bf16x8*)(ph + off);
            bf16x8 bl = *(const bf16x8*)(pl + off);
#pragma unroll
            for (int rt = 0; rt < 4; ++rt) {
                ac[rt][ct] = __builtin_amdgcn_mfma_f32_16x16x32_bf16(ah[rt], bh, ac[rt][ct], 0, 0, 0);
                ac[rt][ct] = __builtin_amdgcn_mfma_f32_16x16x32_bf16(ah[rt], bl, ac[rt][ct], 0, 0, 0);
                ac[rt][ct] = __builtin_amdgcn_mfma_f32_16x16x32_bf16(al[rt], bh, ac[rt][ct], 0, 0, 0);
            }
        }
        if (kc < 7) consume(Ln, kc + 1, (kc + 1) & 1);  // vmcnt wait lands HERE
    }

    // ---- t / norm reductions ----
    __syncthreads();
    if (K >= 0) {
        *(float4*)(tredf + cch * WTS + pos4) = *(float4*)tp;
        float q2 = np;
        for (int off2 = 32; off2 > 0; off2 >>= 1) q2 += __shfl_down(q2, off2);
        if (lane == 0) nred[wvi] = q2;
    }
    __syncthreads();
    if (K >= 0) {
        if (tid < NT) {
            float s = 0.f;
#pragma unroll
            for (int g = 0; g < 32; ++g) s += tredf[g * WTS + tid];
            ts[tid] = s;
        }
        if (tid == 0)
            atomicAdd(&acc[512 + K * 8 + b], nred[0] + nred[1] + nred[2] + nred[3]);
    }
    __syncthreads();   // ts ready; tred reads done (wt aliases everything)

    // ---- transpose acc into wt ----
#pragma unroll
    for (int rt = 0; rt < 4; ++rt)
#pragma unroll
        for (int ct = 0; ct < 2; ++ct) {
            int col = ct * 16 + r15;
            int r0 = mbase + rt * 16 + qq * 4;
#pragma unroll
            for (int reg = 0; reg < 4; ++reg)
                wt[(r0 + reg) * WTS + col] = ac[rt][ct][reg];
        }
    __syncthreads();

    // ---- coalesced epilogue: K<0 write Z; K>=0 w' = wt - Z*t, write + dots ----
    float dp[K >= 0 ? K + 1 : 1];
#pragma unroll
    for (int j = 0; j < (K >= 0 ? K + 1 : 1); ++j) dp[j] = 0.f;
#pragma unroll
    for (int rr = 0; rr < 8; ++rr) {
        int row = rr * 32 + (tid >> 3);
        int col = (tid & 7) * 4;
        float4 wv4 = *(const float4*)(wt + row * WTS + col);
        size_t it = tb + (size_t)(row * NT + col);                 // tile-major
        if (K < 0) {
            ushort4 zh4, zl4;
            unsigned short h0 = f2b(wv4.x), h1 = f2b(wv4.y);
            unsigned short h2 = f2b(wv4.z), h3 = f2b(wv4.w);
            zh4.x = h0; zh4.y = h1; zh4.z = h2; zh4.w = h3;
            zl4.x = f2b(wv4.x - b2f(h0)); zl4.y = f2b(wv4.y - b2f(h1));
            zl4.z = f2b(wv4.z - b2f(h2)); zl4.w = f2b(wv4.w - b2f(h3));
            *(ushort4*)(Zh + it) = zh4;
            *(ushort4*)(Zl + it) = zl4;
        } else {
            size_t is = boff + (size_t)row * HWn + sbase + col;    // std (v)
            ushort4 zh4 = *(const ushort4*)(Zh + it);
            ushort4 zl4 = *(const ushort4*)(Zl + it);
            float z0 = b2f(zh4.x) + b2f(zl4.x), z1 = b2f(zh4.y) + b2f(zl4.y);
            float z2 = b2f(zh4.z) + b2f(zl4.z), z3 = b2f(zh4.w) + b2f(zl4.w);
            float4 wf;
            wf.x = wv4.x - z0 * ts[col + 0];
            wf.y = wv4.y - z1 * ts[col + 1];
            wf.z = wv4.z - z2 * ts[col + 2];
            wf.w = wv4.w - z3 * ts[col + 3];
            *(float4*)(w + it) = wf;
            float4 vv4 = *(const float4*)(v + is);
            dp[0] = fmaf(wf.x, vv4.x, dp[0]);
            dp[0] = fmaf(wf.y, vv4.y, dp[0]);
            dp[0] = fmaf(wf.z, vv4.z, dp[0]);
            dp[0] = fmaf(wf.w, vv4.w, dp[0]);
#pragma unroll
            for (int j = 1; j <= (K >= 0 ? K : 0); ++j) {
                ushort4 u = *(const ushort4*)(Qb + (size_t)(j - 1) * NTOT + it);
                dp[j] = fmaf(wf.x, b2f(u.x), dp[j]);
                dp[j] = fmaf(wf.y, b2f(u.y), dp[j]);
                dp[j] = fmaf(wf.z, b2f(u.z), dp[j]);
                dp[j] = fmaf(wf.w, b2f(u.w), dp[j]);
            }
        }
    }
    if (K >= 0) {
#pragma unroll
        for (int j = 0; j <= K; ++j) {
            float q2 = dp[j];
            for (int off2 = 32; off2 > 0; off2 >>= 1) q2 += __shfl_down(q2, off2);
            if (lane == 0) dred[wvi][j] = q2;
        }
        __syncthreads();
        if (tid <= K)
            atomicAdd(&acc[(K * 8 + tid) * 8 + b],
                      dred[0][tid] + dred[1][tid] + dred[2][tid] + dred[3][tid]);
    }
}

// ---------------- expm of 9x9 per batch (fp64); emits combine coeffs ----------
__global__ __launch_bounds__(128) void expm_kernel(const float* __restrict__ acc,
                                                   float* __restrict__ coordsOut) {
    __shared__ double Am[81], Pm[81], Tm[81];
    __shared__ double ssc;
    __shared__ int sn;
    const int b = blockIdx.x;
    const int t = threadIdx.x;
    const int r = t / 9, c = t % 9;
    double m[8];
    m[0] = sqrt((double)acc[512 + b]);
    for (int j = 1; j < 8; ++j) m[j] = sqrt((double)acc[512 + j * 8 + b]) + 1e-12 * m[j - 1];
    if (t < 81) {
        double val = 0.0;
        if (r < 8 && c < 8) {
            if (r <= c) val = TEND * (double)acc[(c * 8 + r) * 8 + b] / (m[r] * m[c]);
            else if (r == c + 1) val = TEND * sqrt((double)acc[512 + r * 8 + b]) / m[c];
        }
        if (r == 0 && c == 8) val = TEND;
        Am[t] = val;
    }
    __syncthreads();
    if (t == 0) {
        double mx = 0.0;
        for (int rr = 0; rr < 9; ++rr) {
            double s = 0.0;
            for (int cc = 0; cc < 9; ++cc) s += fabs(Am[rr * 9 + cc]);
            if (s > mx) mx = s;
        }
        int n = 0;
        while (mx > 0.25 && n < 48) { mx *= 0.5; ++n; }
        double sc = 1.0;
        for (int ii = 0; ii < n; ++ii) sc *= 0.5;
        sn = n; ssc = sc;
    }
    __syncthreads();
    if (t < 81) Am[t] *= ssc;
    __syncthreads();
    if (t < 81) Pm[t] = (r == c) ? 1.0 : 0.0;
    __syncthreads();
    for (int i = 20; i >= 1; --i) {
        if (t < 81) {
            double s = 0.0;
            for (int k = 0; k < 9; ++k) s += Am[r * 9 + k] * Pm[k * 9 + c];
            Tm[t] = ((r == c) ? 1.0 : 0.0) + s / (double)i;
        }
        __syncthreads();
        if (t < 81) Pm[t] = Tm[t];
        __syncthreads();
    }
    int n = sn;
    for (int q = 0; q < n; ++q) {
        if (t < 81) {
            double s = 0.0;
            for (int k = 0; k < 9; ++k) s += Pm[r * 9 + k] * Pm[k * 9 + c];
            Tm[t] = s;
        }
        __syncthreads();
        if (t < 81) Pm[t] = Tm[t];
        __syncthreads();
    }
    if (t < 8) coordsOut[b * 8 + t] = (float)(Pm[t * 9 + 8] * m[0] / m[t]);
}

// ------ out = coeff_0*v + sum_{j=1..7} coeff_j * U_j (tile-major bf16 Q) ------
__global__ __launch_bounds__(256) void combine_kernel(const unsigned short* __restrict__ Qb,
                                                      const float* __restrict__ v,
                                                      const float* __restrict__ coords,
                                                      float* __restrict__ out) {
    int t = blockIdx.x, b = blockIdx.y;
    const size_t boff = (size_t)b * FB;
    const size_t tb = ((size_t)b * TPB + t) * TSZ;
    float cf[8];
#pragma unroll
    for (int j = 0; j < 8; ++j) cf[j] = coords[b * 8 + j];
    int rg = threadIdx.x >> 3;
    int pos4 = (threadIdx.x & 7) * 4;
#pragma unroll
    for (int ri = 0; ri < 8; ++ri) {
        int r = ri * 32 + rg;
        size_t it = tb + (size_t)(r * NT + pos4);
        size_t is = boff + (size_t)r * HWn + t * NT + pos4;
        float4 vv = *(const float4*)(v + is);
        float a[4] = {cf[0] * vv.x, cf[0] * vv.y, cf[0] * vv.z, cf[0] * vv.w};
#pragma unroll
        for (int j = 1; j < 8; ++j) {
            ushort4 u = *(const ushort4*)(Qb + (size_t)(j - 1) * NTOT + it);
            a[0] = fmaf(cf[j], b2f(u.x), a[0]);
            a[1] = fmaf(cf[j], b2f(u.y), a[1]);
            a[2] = fmaf(cf[j], b2f(u.z), a[2]);
            a[3] = fmaf(cf[j], b2f(u.w), a[3]);
        }
        float4 o = {a[0], a[1], a[2], a[3]};
        *(float4*)(out + is) = o;
    }
}

extern "C" void kernel_launch(void* const* d_in, const int* in_sizes, int n_in,
                              void* d_out, int out_size, void* d_ws, size_t ws_size,
                              hipStream_t stream) {
    const float* s0 = (const float*)d_in[0];
    const float* v  = (const float*)d_in[1];
    const float* W  = (const float*)d_in[2];
    float* out = (float*)d_out;

    // ws (floats): [acc 576 | coords 64 | pad->1024 | Whs 32768 | Wls 32768 |
    //               Zh bf16 NTOT | Zl bf16 NTOT | Qb bf16 7*NTOT]  (r4 footprint)
    float* ws     = (float*)d_ws;
    float* acc    = ws;
    float* coords = ws + 576;
    unsigned short* Whs = (unsigned short*)(ws + 1024);
    unsigned short* Wls = Whs + 65536;
    unsigned short* Zh  = (unsigned short*)(ws + 1024 + 65536);
    unsigned short* Zl  = Zh + NTOT;
    unsigned short* Qb  = Zh + 2 * (size_t)NTOT;   // 7 bf16 fields, tile-major
    float* w      = out;   // working A-output (fp32, tile-major during steps)

    init_kernel<<<dim3(1), dim3(256), 0, stream>>>(ws);
    wsplit_kernel<<<dim3(8, 16), dim3(64), 0, stream>>>(W, Whs, Wls);

    dim3 ga(TPB, 8), blk(256);
    // Z = W @ s0 (once, bf16 hi/lo, tile-major)
    step_kernel<-1><<<ga, blk, 0, stream>>>(v, s0, Whs, Wls, Qb, acc, w, Zh, Zl);
#define STEPK(K) step_kernel<K><<<ga, blk, 0, stream>>>(v, s0, Whs, Wls, Qb, acc, w, Zh, Zl);
    STEPK(0) STEPK(1) STEPK(2) STEPK(3) STEPK(4) STEPK(5) STEPK(6) STEPK(7)
#undef STEPK

    expm_kernel<<<dim3(8), dim3(128), 0, stream>>>(acc, coords);
    combine_kernel<<<dim3(TPB, 8), blk, 0, stream>>>(Qb, v, coords, out);
}

// Round 13
// 510.872 us; speedup vs baseline: 1.3510x; 1.0019x over previous
//
#include <hip/hip_runtime.h>
#include <math.h>

#define Bn   8
#define Cn   256
#define HWn  4096
#define FB   (Cn * HWn)      // 1048576 elems per batch-field
#define NTOT (Bn * FB)       // 8388608 elems per field
#define TEND 1.0
#define EPSK 1e-12f
#define NT   32              // apply N-tile (positions)
#define TPB  128             // tiles per batch
#define TSZ  8192            // elems per (b,tile): 256*32
#define RS   40              // staging row stride (shorts)
#define WTS  36              // wt / tred row stride (floats)

typedef float f32x4 __attribute__((ext_vector_type(4)));
typedef short bf16x8 __attribute__((ext_vector_type(8)));

__device__ inline float b2f(unsigned int u) {
    return __uint_as_float(u << 16);
}
__device__ inline unsigned short f2b(float f) {  // RNE
    unsigned u = __float_as_uint(f);
    unsigned r = u + 0x7FFFu + ((u >> 16) & 1u);
    return (unsigned short)(r >> 16);
}

// acc layout (floats, 8 batches each):
//   D[k][j] at acc[(k*8+j)*8 + b];  Nsq[j] at acc[512 + j*8 + b];  coords at acc+576

__global__ void init_kernel(float* __restrict__ p) {
    for (int i = threadIdx.x; i < 1024; i += 256) p[i] = 0.0f;
}

// ---- split W into bf16 hi/lo in MFMA-A staged layout ----
__global__ void wsplit_kernel(const float* __restrict__ W,
                              unsigned short* __restrict__ Whs,
                              unsigned short* __restrict__ Wls) {
    int kc = blockIdx.x, mt = blockIdx.y, l = threadIdx.x;
    int m = mt * 16 + (l & 15);
    int k0 = kc * 32 + (l >> 4) * 8;
#pragma unroll
    for (int j = 0; j < 8; ++j) {
        float wv = W[m * 256 + k0 + j];
        unsigned short h = f2b(wv);
        unsigned short lo = f2b(wv - b2f(h));
        int idx = ((kc * 16 + mt) * 64 + l) * 8 + j;
        Whs[idx] = h; Wls[idx] = lo;
    }
}

// ================= fused Krylov step K (K = 0..7) =============================
// Grid (128,8) = 1024 blocks = 4 blocks/CU, 256 threads, (256,2) VGPR cap 128
// (toolchain rule: cap = 256/arg2; arg2=4 -> 64-cap spill, r6/r8/r11).
// Z ELIMINATED via t-fold (r2/r3-verified numerics): w' = W@(s0.*(xr - t)),
// t = colsum(s0.*xr). No Z field, no Z-build dispatch, single accumulator.
//  phase 1: streaming CGS x = w - sum cj*basis -> Q_{K-1} bf16 (tile-major),
//           partials t, ||x||^2. No LDS.
//  reduce t -> ts[32].
//  phase 2: re-read s0/Q_K (L2-hot: per-XCD phase-2 set ~1.5MB << 4MB L2);
//           P = s0*(xr - t) hi/lo -> swizzled LDS dbuf -> ac += W@P.
//  epilogue: w' = ac; LDS transpose -> coalesced tile-major write + dots D[K][j].
template <int K>
__global__ __launch_bounds__(256, 2) void step_kernel(
        const float* __restrict__ v, const float* __restrict__ s0,
        const unsigned short* __restrict__ Whs, const unsigned short* __restrict__ Wls,
        unsigned short* __restrict__ Qb, float* __restrict__ acc,
        float* __restrict__ w) {
    __shared__ __align__(16) char smem_u[36864];
    short* Ph0 = (short*)smem_u;                  // 32*RS*2 = 2560 B each
    short* Ph1 = (short*)(smem_u + 2560);
    short* Pl0 = (short*)(smem_u + 5120);
    short* Pl1 = (short*)(smem_u + 7680);
    float* tredf = (float*)(smem_u + 10240);      // 32*WTS*4 = 4608 B
    float* wt    = (float*)smem_u;                // 256*WTS*4 = 36864 B (epilogue)
    __shared__ float ts[NT];
    __shared__ float nred[4];
    __shared__ float dred[4][8];

    const int tid = threadIdx.x;
    const int lane = tid & 63, wvi = tid >> 6;
    const int b = blockIdx.y;
    const int tIdx = blockIdx.x;
    const int sbase = tIdx * NT;
    const size_t boff = (size_t)b * FB;
    const size_t tb = ((size_t)b * TPB + tIdx) * TSZ;
    const int mbase = wvi * 64;        // 64 output rows per wave
    const int cch = tid >> 3;          // 0..31: channel within chunk
    const int pos4 = (tid & 7) * 4;    // 0..28
    const int codd = cch & 1;
    const int c2s = cch >> 1;          // 0..15: 4-byte slot index

    // ---- CGS coefficients from previous step's dots ----
    float cj[K > 0 ? K : 1];
    if (K > 0) {
        float mm[K > 0 ? K : 1];
        mm[0] = sqrtf(acc[512 + b]);
#pragma unroll
        for (int j = 1; j < K; ++j) mm[j] = sqrtf(acc[512 + j * 8 + b]) + EPSK * mm[j - 1];
#pragma unroll
        for (int j = 0; j < K; ++j)
            cj[j] = acc[((K - 1) * 8 + j) * 8 + b] / (mm[j] * mm[j]);
    }
    unsigned short* QK = Qb + (size_t)(K > 0 ? K - 1 : 0) * NTOT;

    // ---- phase 1: streaming CGS + t/norm partials (no LDS) ----
    float tp[4] = {0.f, 0.f, 0.f, 0.f};
    float np = 0.f;
    for (int kc = 0; kc < 8; ++kc) {
        const size_t os = boff + (size_t)(kc * 32 + cch) * HWn + sbase + pos4;
        const size_t ot = tb + (size_t)((kc * 32 + cch) * NT + pos4);
        float4 s4 = *(const float4*)(s0 + os);
        float se[4] = {s4.x, s4.y, s4.z, s4.w};
        float xr[4];
        if (K == 0) {
            float4 x4 = *(const float4*)(v + os);
            xr[0] = x4.x; xr[1] = x4.y; xr[2] = x4.z; xr[3] = x4.w;
        } else {
            float4 w4 = *(const float4*)(w + ot);
            float4 v4 = *(const float4*)(v + os);
            float xe[4];
            xe[0] = fmaf(-cj[0], v4.x, w4.x);
            xe[1] = fmaf(-cj[0], v4.y, w4.y);
            xe[2] = fmaf(-cj[0], v4.z, w4.z);
            xe[3] = fmaf(-cj[0], v4.w, w4.w);
#pragma unroll
            for (int j = 1; j < K; ++j) {
                ushort4 u = *(const ushort4*)(Qb + (size_t)(j - 1) * NTOT + ot);
                xe[0] = fmaf(-cj[j], b2f(u.x), xe[0]);
                xe[1] = fmaf(-cj[j], b2f(u.y), xe[1]);
                xe[2] = fmaf(-cj[j], b2f(u.z), xe[2]);
                xe[3] = fmaf(-cj[j], b2f(u.w), xe[3]);
            }
            unsigned h0 = f2b(xe[0]), h1 = f2b(xe[1]);
            unsigned h2 = f2b(xe[2]), h3 = f2b(xe[3]);
            ushort4 o;
            o.x = (unsigned short)h0; o.y = (unsigned short)h1;
            o.z = (unsigned short)h2; o.w = (unsigned short)h3;
            *(ushort4*)(QK + ot) = o;
            xr[0] = b2f(h0); xr[1] = b2f(h1); xr[2] = b2f(h2); xr[3] = b2f(h3);
        }
#pragma unroll
        for (int i = 0; i < 4; ++i) {
            np = fmaf(xr[i], xr[i], np);
            tp[i] = fmaf(xr[i], se[i], tp[i]);
        }
    }
    // ---- reduce t and ||x||^2 ----
    *(float4*)(tredf + cch * WTS + pos4) = *(float4*)tp;
    {
        float q2 = np;
        for (int off2 = 32; off2 > 0; off2 >>= 1) q2 += __shfl_down(q2, off2);
        if (lane == 0) nred[wvi] = q2;
    }
    __syncthreads();
    if (tid < NT) {
        float s = 0.f;
#pragma unroll
        for (int g = 0; g < 32; ++g) s += tredf[g * WTS + tid];
        ts[tid] = s;
    }
    if (tid == 0)
        atomicAdd(&acc[512 + K * 8 + b], nred[0] + nred[1] + nred[2] + nred[3]);
    __syncthreads();   // ts ready

    // paired-write: partner channel is cch^1 -> lane tid^8. XOR-swizzled slot.
    auto wr2 = [&](short* buf, unsigned x01, unsigned x23) {
        unsigned p01 = (unsigned)__shfl_xor((int)x01, 8);
        unsigned p23 = (unsigned)__shfl_xor((int)x23, 8);
        unsigned mine = codd ? x23 : x01;
        unsigned theirs = codd ? p23 : p01;
        unsigned w0, w1;
        if (codd) {
            w0 = (theirs & 0xFFFFu) | (mine << 16);
            w1 = (theirs >> 16) | (mine & 0xFFFF0000u);
        } else {
            w0 = (mine & 0xFFFFu) | (theirs << 16);
            w1 = (mine >> 16) | (theirs & 0xFFFF0000u);
        }
        int P0 = pos4 + 2 * codd;
        int slot = c2s ^ (((P0 >> 3) & 3) << 2);
        *(unsigned*)(buf + P0 * RS + slot * 2) = w0;
        *(unsigned*)(buf + (P0 + 1) * RS + slot * 2) = w1;
    };

    // phase-2 stage: re-read s0 / xr (L2-hot), P = s0*(xr - t), hi/lo -> LDS
    auto stage = [&](int kc, int bb) {
        const size_t os = boff + (size_t)(kc * 32 + cch) * HWn + sbase + pos4;
        const size_t ot = tb + (size_t)((kc * 32 + cch) * NT + pos4);
        float4 s4 = *(const float4*)(s0 + os);
        float se[4] = {s4.x, s4.y, s4.z, s4.w};
        float xr[4];
        if (K == 0) {
            float4 x4 = *(const float4*)(v + os);
            xr[0] = x4.x; xr[1] = x4.y; xr[2] = x4.z; xr[3] = x4.w;
        } else {
            ushort4 u = *(const ushort4*)(QK + ot);    // just written, cache-hot
            xr[0] = b2f(u.x); xr[1] = b2f(u.y); xr[2] = b2f(u.z); xr[3] = b2f(u.w);
        }
        unsigned phx[4], plx[4];
#pragma unroll
        for (int i = 0; i < 4; ++i) {
            float pe = se[i] * (xr[i] - ts[pos4 + i]);
            unsigned hp = f2b(pe);
            phx[i] = hp; plx[i] = f2b(pe - b2f((unsigned short)hp));
        }
        wr2(bb ? Ph1 : Ph0, phx[0] | (phx[1] << 16), phx[2] | (phx[3] << 16));
        wr2(bb ? Pl1 : Pl0, plx[0] | (plx[1] << 16), plx[2] | (plx[3] << 16));
    };

    f32x4 ac[4][2];
#pragma unroll
    for (int i = 0; i < 4; ++i)
#pragma unroll
        for (int j = 0; j < 2; ++j) ac[i][j] = (f32x4){0.f, 0.f, 0.f, 0.f};

    const int r15 = lane & 15, qq = lane >> 4;
    stage(0, 0);
    for (int kc = 0; kc < 8; ++kc) {
        __syncthreads();               // buf[kc&1] staged; buf[kc^1] reads done
        bf16x8 ah[4], al[4];
#pragma unroll
        for (int rt = 0; rt < 4; ++rt) {
            int mt = wvi * 4 + rt;
            ah[rt] = *(const bf16x8*)(Whs + (size_t)kc * 8192 + (mt * 64 + lane) * 8);
            al[rt] = *(const bf16x8*)(Wls + (size_t)kc * 8192 + (mt * 64 + lane) * 8);
        }
        if (kc < 7) stage(kc + 1, (kc + 1) & 1);
        const short* ph = (kc & 1) ? Ph1 : Ph0;
        const short* pl = (kc & 1) ? Pl1 : Pl0;
#pragma unroll
        for (int ct = 0; ct < 2; ++ct) {
            int n = ct * 16 + r15;
            int grp = qq ^ ((n >> 3) & 3);
            int off = n * RS + grp * 8;
            bf16x8 bh = *(const bf16x8*)(ph + off);
            bf16x8 bl = *(const bf16x8*)(pl + off);
#pragma unroll
            for (int rt = 0; rt < 4; ++rt) {
                ac[rt][ct] = __builtin_amdgcn_mfma_f32_16x16x32_bf16(ah[rt], bh, ac[rt][ct], 0, 0, 0);
                ac[rt][ct] = __builtin_amdgcn_mfma_f32_16x16x32_bf16(ah[rt], bl, ac[rt][ct], 0, 0, 0);
                ac[rt][ct] = __builtin_amdgcn_mfma_f32_16x16x32_bf16(al[rt], bh, ac[rt][ct], 0, 0, 0);
            }
        }
    }

    // ---- transpose ac into wt (wt aliases staging; all LDS reads done) ----
    __syncthreads();
#pragma unroll
    for (int rt = 0; rt < 4; ++rt)
#pragma unroll
        for (int ct = 0; ct < 2; ++ct) {
            int col = ct * 16 + r15;
            int r0 = mbase + rt * 16 + qq * 4;
#pragma unroll
            for (int reg = 0; reg < 4; ++reg)
                wt[(r0 + reg) * WTS + col] = ac[rt][ct][reg];
        }
    __syncthreads();

    // ---- coalesced epilogue: tile-major w' write + dots D[K][j] ----
    float dp[K + 1];
#pragma unroll
    for (int j = 0; j <= K; ++j) dp[j] = 0.f;
#pragma unroll
    for (int rr = 0; rr < 8; ++rr) {
        int row = rr * 32 + (tid >> 3);
        int col = (tid & 7) * 4;
        float4 wf = *(const float4*)(wt + row * WTS + col);
        size_t it = tb + (size_t)(row * NT + col);                 // tile-major
        size_t is = boff + (size_t)row * HWn + sbase + col;        // std (v)
        *(float4*)(w + it) = wf;
        float4 vv4 = *(const float4*)(v + is);
        dp[0] = fmaf(wf.x, vv4.x, dp[0]);
        dp[0] = fmaf(wf.y, vv4.y, dp[0]);
        dp[0] = fmaf(wf.z, vv4.z, dp[0]);
        dp[0] = fmaf(wf.w, vv4.w, dp[0]);
#pragma unroll
        for (int j = 1; j <= K; ++j) {
            ushort4 u = *(const ushort4*)(Qb + (size_t)(j - 1) * NTOT + it);
            dp[j] = fmaf(wf.x, b2f(u.x), dp[j]);
            dp[j] = fmaf(wf.y, b2f(u.y), dp[j]);
            dp[j] = fmaf(wf.z, b2f(u.z), dp[j]);
            dp[j] = fmaf(wf.w, b2f(u.w), dp[j]);
        }
    }
#pragma unroll
    for (int j = 0; j <= K; ++j) {
        float q2 = dp[j];
        for (int off2 = 32; off2 > 0; off2 >>= 1) q2 += __shfl_down(q2, off2);
        if (lane == 0) dred[wvi][j] = q2;
    }
    __syncthreads();
    if (tid <= K)
        atomicAdd(&acc[(K * 8 + tid) * 8 + b],
                  dred[0][tid] + dred[1][tid] + dred[2][tid] + dred[3][tid]);
}

// ---------------- expm of 9x9 per batch (fp64); emits combine coeffs ----------
__global__ __launch_bounds__(128) void expm_kernel(const float* __restrict__ acc,
                                                   float* __restrict__ coordsOut) {
    __shared__ double Am[81], Pm[81], Tm[81];
    __shared__ double ssc;
    __shared__ int sn;
    const int b = blockIdx.x;
    const int t = threadIdx.x;
    const int r = t / 9, c = t % 9;
    double m[8];
    m[0] = sqrt((double)acc[512 + b]);
    for (int j = 1; j < 8; ++j) m[j] = sqrt((double)acc[512 + j * 8 + b]) + 1e-12 * m[j - 1];
    if (t < 81) {
        double val = 0.0;
        if (r < 8 && c < 8) {
            if (r <= c) val = TEND * (double)acc[(c * 8 + r) * 8 + b] / (m[r] * m[c]);
            else if (r == c + 1) val = TEND * sqrt((double)acc[512 + r * 8 + b]) / m[c];
        }
        if (r == 0 && c == 8) val = TEND;
        Am[t] = val;
    }
    __syncthreads();
    if (t == 0) {
        double mx = 0.0;
        for (int rr = 0; rr < 9; ++rr) {
            double s = 0.0;
            for (int cc = 0; cc < 9; ++cc) s += fabs(Am[rr * 9 + cc]);
            if (s > mx) mx = s;
        }
        int n = 0;
        while (mx > 0.25 && n < 48) { mx *= 0.5; ++n; }
        double sc = 1.0;
        for (int ii = 0; ii < n; ++ii) sc *= 0.5;
        sn = n; ssc = sc;
    }
    __syncthreads();
    if (t < 81) Am[t] *= ssc;
    __syncthreads();
    if (t < 81) Pm[t] = (r == c) ? 1.0 : 0.0;
    __syncthreads();
    for (int i = 20; i >= 1; --i) {
        if (t < 81) {
            double s = 0.0;
            for (int k = 0; k < 9; ++k) s += Am[r * 9 + k] * Pm[k * 9 + c];
            Tm[t] = ((r == c) ? 1.0 : 0.0) + s / (double)i;
        }
        __syncthreads();
        if (t < 81) Pm[t] = Tm[t];
        __syncthreads();
    }
    int n = sn;
    for (int q = 0; q < n; ++q) {
        if (t < 81) {
            double s = 0.0;
            for (int k = 0; k < 9; ++k) s += Pm[r * 9 + k] * Pm[k * 9 + c];
            Tm[t] = s;
        }
        __syncthreads();
        if (t < 81) Pm[t] = Tm[t];
        __syncthreads();
    }
    if (t < 8) coordsOut[b * 8 + t] = (float)(Pm[t * 9 + 8] * m[0] / m[t]);
}

// ------ out = coeff_0*v + sum_{j=1..7} coeff_j * U_j (tile-major bf16 Q) ------
__global__ __launch_bounds__(256) void combine_kernel(const unsigned short* __restrict__ Qb,
                                                      const float* __restrict__ v,
                                                      const float* __restrict__ coords,
                                                      float* __restrict__ out) {
    int t = blockIdx.x, b = blockIdx.y;
    const size_t boff = (size_t)b * FB;
    const size_t tb = ((size_t)b * TPB + t) * TSZ;
    float cf[8];
#pragma unroll
    for (int j = 0; j < 8; ++j) cf[j] = coords[b * 8 + j];
    int rg = threadIdx.x >> 3;
    int pos4 = (threadIdx.x & 7) * 4;
#pragma unroll
    for (int ri = 0; ri < 8; ++ri) {
        int r = ri * 32 + rg;
        size_t it = tb + (size_t)(r * NT + pos4);
        size_t is = boff + (size_t)r * HWn + t * NT + pos4;
        float4 vv = *(const float4*)(v + is);
        float a[4] = {cf[0] * vv.x, cf[0] * vv.y, cf[0] * vv.z, cf[0] * vv.w};
#pragma unroll
        for (int j = 1; j < 8; ++j) {
            ushort4 u = *(const ushort4*)(Qb + (size_t)(j - 1) * NTOT + it);
            a[0] = fmaf(cf[j], b2f(u.x), a[0]);
            a[1] = fmaf(cf[j], b2f(u.y), a[1]);
            a[2] = fmaf(cf[j], b2f(u.z), a[2]);
            a[3] = fmaf(cf[j], b2f(u.w), a[3]);
        }
        float4 o = {a[0], a[1], a[2], a[3]};
        *(float4*)(out + is) = o;
    }
}

extern "C" void kernel_launch(void* const* d_in, const int* in_sizes, int n_in,
                              void* d_out, int out_size, void* d_ws, size_t ws_size,
                              hipStream_t stream) {
    const float* s0 = (const float*)d_in[0];
    const float* v  = (const float*)d_in[1];
    const float* W  = (const float*)d_in[2];
    float* out = (float*)d_out;

    // ws (floats): [acc 576 | coords 64 | pad->1024 | Whs 32768 | Wls 32768 |
    //               Qb bf16 7*NTOT]   (Z eliminated)
    float* ws     = (float*)d_ws;
    float* acc    = ws;
    float* coords = ws + 576;
    unsigned short* Whs = (unsigned short*)(ws + 1024);
    unsigned short* Wls = Whs + 65536;
    unsigned short* Qb  = (unsigned short*)(ws + 1024 + 65536);  // 7 bf16 fields, tile-major
    float* w      = out;   // working A-output (fp32, tile-major during steps)

    init_kernel<<<dim3(1), dim3(256), 0, stream>>>(ws);
    wsplit_kernel<<<dim3(8, 16), dim3(64), 0, stream>>>(W, Whs, Wls);

    dim3 ga(TPB, 8), blk(256);
#define STEPK(K) step_kernel<K><<<ga, blk, 0, stream>>>(v, s0, Whs, Wls, Qb, acc, w);
    STEPK(0) STEPK(1) STEPK(2) STEPK(3) STEPK(4) STEPK(5) STEPK(6) STEPK(7)
#undef STEPK

    expm_kernel<<<dim3(8), dim3(128), 0, stream>>>(acc, coords);
    combine_kernel<<<dim3(TPB, 8), blk, 0, stream>>>(Qb, v, coords, out);
}

// Round 14
// 501.240 us; speedup vs baseline: 1.3770x; 1.0192x over previous
//
#include <hip/hip_runtime.h>
#include <math.h>

#define Bn   8
#define Cn   256
#define HWn  4096
#define FB   (Cn * HWn)      // 1048576 elems per batch-field
#define NTOT (Bn * FB)       // 8388608 elems per field
#define TEND 1.0
#define EPSK 1e-12f
#define NT   32              // apply N-tile (positions)
#define TPB  128             // tiles per batch
#define TSZ  8192            // elems per (b,tile): 256*32
#define RS   40              // staging row stride (shorts)
#define WTS  36              // wt / tred row stride (floats)

typedef float f32x4 __attribute__((ext_vector_type(4)));
typedef short bf16x8 __attribute__((ext_vector_type(8)));

__device__ inline float b2f(unsigned int u) {
    return __uint_as_float(u << 16);
}
__device__ inline unsigned short f2b(float f) {  // RNE
    unsigned u = __float_as_uint(f);
    unsigned r = u + 0x7FFFu + ((u >> 16) & 1u);
    return (unsigned short)(r >> 16);
}

// acc layout (floats, 8 batches each):
//   D[k][j] at acc[(k*8+j)*8 + b];  Nsq[j] at acc[512 + j*8 + b];  coords at acc+576

__global__ void init_kernel(float* __restrict__ p) {
    for (int i = threadIdx.x; i < 1024; i += 256) p[i] = 0.0f;
}

// ---- split W into bf16 hi/lo in MFMA-A staged layout ----
__global__ void wsplit_kernel(const float* __restrict__ W,
                              unsigned short* __restrict__ Whs,
                              unsigned short* __restrict__ Wls) {
    int kc = blockIdx.x, mt = blockIdx.y, l = threadIdx.x;
    int m = mt * 16 + (l & 15);
    int k0 = kc * 32 + (l >> 4) * 8;
#pragma unroll
    for (int j = 0; j < 8; ++j) {
        float wv = W[m * 256 + k0 + j];
        unsigned short h = f2b(wv);
        unsigned short lo = f2b(wv - b2f(h));
        int idx = ((kc * 16 + mt) * 64 + l) * 8 + j;
        Whs[idx] = h; Wls[idx] = lo;
    }
}

// ================= fused Krylov step K (K = 0..7) =============================
// Grid (128,8) = 1024 blocks = 4 blocks/CU, 256 threads, (256,2) VGPR cap 128.
// SINGLE PASS + Z ON THE FLY (r7 numerics @ r13 structure): per k-chunk, one
// pass does CGS -> Q_{K-1} bf16, stages P = s0*xr AND S = s0 (hi/lo, swizzled
// LDS dbuf), MFMAs ac += W@P and az += W@S. Epilogue: w' = ac - az*t
// (az == W@s0 exact-on-the-fly), t = colsum(s0*xr). No phase-2 re-read pass.
// LDS: staging 20.5KB + tred 4.6KB union'd under wt 36.9KB -> unchanged,
// 4 blocks/CU preserved. az costs +32 VGPR (88 -> ~120 <= 128 cap, no spill).
template <int K>
__global__ __launch_bounds__(256, 2) void step_kernel(
        const float* __restrict__ v, const float* __restrict__ s0,
        const unsigned short* __restrict__ Whs, const unsigned short* __restrict__ Wls,
        unsigned short* __restrict__ Qb, float* __restrict__ acc,
        float* __restrict__ w) {
    __shared__ __align__(16) char smem_u[36864];
    short* Ph0 = (short*)smem_u;                  // 32*RS*2 = 2560 B each
    short* Ph1 = (short*)(smem_u + 2560);
    short* Pl0 = (short*)(smem_u + 5120);
    short* Pl1 = (short*)(smem_u + 7680);
    short* Sh0 = (short*)(smem_u + 10240);
    short* Sh1 = (short*)(smem_u + 12800);
    short* Sl0 = (short*)(smem_u + 15360);
    short* Sl1 = (short*)(smem_u + 17920);
    float* tredf = (float*)(smem_u + 20480);      // 32*WTS*4 = 4608 B -> 25088
    float* wt    = (float*)smem_u;                // 256*WTS*4 = 36864 B (epilogue)
    __shared__ float ts[NT];
    __shared__ float nred[4];
    __shared__ float dred[4][8];

    const int tid = threadIdx.x;
    const int lane = tid & 63, wvi = tid >> 6;
    const int b = blockIdx.y;
    const int tIdx = blockIdx.x;
    const int sbase = tIdx * NT;
    const size_t boff = (size_t)b * FB;
    const size_t tb = ((size_t)b * TPB + tIdx) * TSZ;
    const int mbase = wvi * 64;        // 64 output rows per wave
    const int cch = tid >> 3;          // 0..31: channel within chunk
    const int pos4 = (tid & 7) * 4;    // 0..28
    const int codd = cch & 1;
    const int c2s = cch >> 1;          // 0..15: 4-byte slot index

    // ---- CGS coefficients from previous step's dots ----
    float cj[K > 0 ? K : 1];
    if (K > 0) {
        float mm[K > 0 ? K : 1];
        mm[0] = sqrtf(acc[512 + b]);
#pragma unroll
        for (int j = 1; j < K; ++j) mm[j] = sqrtf(acc[512 + j * 8 + b]) + EPSK * mm[j - 1];
#pragma unroll
        for (int j = 0; j < K; ++j)
            cj[j] = acc[((K - 1) * 8 + j) * 8 + b] / (mm[j] * mm[j]);
    }
    unsigned short* QK = Qb + (size_t)(K > 0 ? K - 1 : 0) * NTOT;

    float tp[4] = {0.f, 0.f, 0.f, 0.f};
    float np = 0.f;

    // paired-write: partner channel is cch^1 -> lane tid^8. XOR-swizzled slot.
    auto wr2 = [&](short* buf, unsigned x01, unsigned x23) {
        unsigned p01 = (unsigned)__shfl_xor((int)x01, 8);
        unsigned p23 = (unsigned)__shfl_xor((int)x23, 8);
        unsigned mine = codd ? x23 : x01;
        unsigned theirs = codd ? p23 : p01;
        unsigned w0, w1;
        if (codd) {
            w0 = (theirs & 0xFFFFu) | (mine << 16);
            w1 = (theirs >> 16) | (mine & 0xFFFF0000u);
        } else {
            w0 = (mine & 0xFFFFu) | (theirs << 16);
            w1 = (mine >> 16) | (theirs & 0xFFFF0000u);
        }
        int P0 = pos4 + 2 * codd;
        int slot = c2s ^ (((P0 >> 3) & 3) << 2);
        *(unsigned*)(buf + P0 * RS + slot * 2) = w0;
        *(unsigned*)(buf + (P0 + 1) * RS + slot * 2) = w1;
    };

    // single-pass stage: CGS -> Q_K write, pack P = s0*xr and S = s0 (hi/lo)
    auto stage = [&](int kc, int bb) {
        const size_t os = boff + (size_t)(kc * 32 + cch) * HWn + sbase + pos4;
        const size_t ot = tb + (size_t)((kc * 32 + cch) * NT + pos4);
        float4 s4 = *(const float4*)(s0 + os);
        float se[4] = {s4.x, s4.y, s4.z, s4.w};
        float xr[4];
        if (K == 0) {
            float4 x4 = *(const float4*)(v + os);
            xr[0] = x4.x; xr[1] = x4.y; xr[2] = x4.z; xr[3] = x4.w;
        } else {
            float4 w4 = *(const float4*)(w + ot);
            float4 v4 = *(const float4*)(v + os);
            float xe[4];
            xe[0] = fmaf(-cj[0], v4.x, w4.x);
            xe[1] = fmaf(-cj[0], v4.y, w4.y);
            xe[2] = fmaf(-cj[0], v4.z, w4.z);
            xe[3] = fmaf(-cj[0], v4.w, w4.w);
#pragma unroll
            for (int j = 1; j < K; ++j) {
                ushort4 u = *(const ushort4*)(Qb + (size_t)(j - 1) * NTOT + ot);
                xe[0] = fmaf(-cj[j], b2f(u.x), xe[0]);
                xe[1] = fmaf(-cj[j], b2f(u.y), xe[1]);
                xe[2] = fmaf(-cj[j], b2f(u.z), xe[2]);
                xe[3] = fmaf(-cj[j], b2f(u.w), xe[3]);
            }
            unsigned h0 = f2b(xe[0]), h1 = f2b(xe[1]);
            unsigned h2 = f2b(xe[2]), h3 = f2b(xe[3]);
            ushort4 o;
            o.x = (unsigned short)h0; o.y = (unsigned short)h1;
            o.z = (unsigned short)h2; o.w = (unsigned short)h3;
            *(ushort4*)(QK + ot) = o;
            xr[0] = b2f(h0); xr[1] = b2f(h1); xr[2] = b2f(h2); xr[3] = b2f(h3);
        }
        unsigned phx[4], plx[4], shx[4], slx[4];
#pragma unroll
        for (int i = 0; i < 4; ++i) {
            np = fmaf(xr[i], xr[i], np);
            tp[i] = fmaf(xr[i], se[i], tp[i]);
            float pe = se[i] * xr[i];
            unsigned hp = f2b(pe);
            phx[i] = hp; plx[i] = f2b(pe - b2f((unsigned short)hp));
            unsigned hs = f2b(se[i]);
            shx[i] = hs; slx[i] = f2b(se[i] - b2f((unsigned short)hs));
        }
        wr2(bb ? Ph1 : Ph0, phx[0] | (phx[1] << 16), phx[2] | (phx[3] << 16));
        wr2(bb ? Pl1 : Pl0, plx[0] | (plx[1] << 16), plx[2] | (plx[3] << 16));
        wr2(bb ? Sh1 : Sh0, shx[0] | (shx[1] << 16), shx[2] | (shx[3] << 16));
        wr2(bb ? Sl1 : Sl0, slx[0] | (slx[1] << 16), slx[2] | (slx[3] << 16));
    };

    f32x4 ac[4][2], az[4][2];
#pragma unroll
    for (int i = 0; i < 4; ++i)
#pragma unroll
        for (int j = 0; j < 2; ++j) {
            ac[i][j] = (f32x4){0.f, 0.f, 0.f, 0.f};
            az[i][j] = (f32x4){0.f, 0.f, 0.f, 0.f};
        }

    const int r15 = lane & 15, qq = lane >> 4;
    stage(0, 0);
    for (int kc = 0; kc < 8; ++kc) {
        __syncthreads();               // buf[kc&1] staged; buf[kc^1] reads done
        bf16x8 ah[4], al[4];
#pragma unroll
        for (int rt = 0; rt < 4; ++rt) {
            int mt = wvi * 4 + rt;
            ah[rt] = *(const bf16x8*)(Whs + (size_t)kc * 8192 + (mt * 64 + lane) * 8);
            al[rt] = *(const bf16x8*)(Wls + (size_t)kc * 8192 + (mt * 64 + lane) * 8);
        }
        if (kc < 7) stage(kc + 1, (kc + 1) & 1);
        const short* ph = (kc & 1) ? Ph1 : Ph0;
        const short* pl = (kc & 1) ? Pl1 : Pl0;
        const short* sh = (kc & 1) ? Sh1 : Sh0;
        const short* sl = (kc & 1) ? Sl1 : Sl0;
#pragma unroll
        for (int ct = 0; ct < 2; ++ct) {
            int n = ct * 16 + r15;
            int grp = qq ^ ((n >> 3) & 3);
            int off = n * RS + grp * 8;
            bf16x8 bh = *(const bf16x8*)(ph + off);
            bf16x8 bl = *(const bf16x8*)(pl + off);
            bf16x8 svh = *(const bf16x8*)(sh + off);
            bf16x8 svl = *(const bf16x8*)(sl + off);
#pragma unroll
            for (int rt = 0; rt < 4; ++rt) {
                ac[rt][ct] = __builtin_amdgcn_mfma_f32_16x16x32_bf16(ah[rt], bh, ac[rt][ct], 0, 0, 0);
                ac[rt][ct] = __builtin_amdgcn_mfma_f32_16x16x32_bf16(ah[rt], bl, ac[rt][ct], 0, 0, 0);
                ac[rt][ct] = __builtin_amdgcn_mfma_f32_16x16x32_bf16(al[rt], bh, ac[rt][ct], 0, 0, 0);
                az[rt][ct] = __builtin_amdgcn_mfma_f32_16x16x32_bf16(ah[rt], svh, az[rt][ct], 0, 0, 0);
                az[rt][ct] = __builtin_amdgcn_mfma_f32_16x16x32_bf16(ah[rt], svl, az[rt][ct], 0, 0, 0);
                az[rt][ct] = __builtin_amdgcn_mfma_f32_16x16x32_bf16(al[rt], svh, az[rt][ct], 0, 0, 0);
            }
        }
    }

    // ---- t / norm reductions (tredf does not alias staging; MFMA reads done) ----
    __syncthreads();
    *(float4*)(tredf + cch * WTS + pos4) = *(float4*)tp;
    {
        float q2 = np;
        for (int off2 = 32; off2 > 0; off2 >>= 1) q2 += __shfl_down(q2, off2);
        if (lane == 0) nred[wvi] = q2;
    }
    __syncthreads();
    if (tid < NT) {
        float s = 0.f;
#pragma unroll
        for (int g = 0; g < 32; ++g) s += tredf[g * WTS + tid];
        ts[tid] = s;
    }
    if (tid == 0)
        atomicAdd(&acc[512 + K * 8 + b], nred[0] + nred[1] + nred[2] + nred[3]);
    __syncthreads();   // ts ready

    // ---- transpose w' = ac - az*t into wt (wt aliases staging+tred) ----
#pragma unroll
    for (int rt = 0; rt < 4; ++rt)
#pragma unroll
        for (int ct = 0; ct < 2; ++ct) {
            int col = ct * 16 + r15;
            int r0 = mbase + rt * 16 + qq * 4;
            float tv = ts[col];
#pragma unroll
            for (int reg = 0; reg < 4; ++reg)
                wt[(r0 + reg) * WTS + col] = ac[rt][ct][reg] - az[rt][ct][reg] * tv;
        }
    __syncthreads();

    // ---- coalesced epilogue: tile-major w' write + dots D[K][j] ----
    float dp[K + 1];
#pragma unroll
    for (int j = 0; j <= K; ++j) dp[j] = 0.f;
#pragma unroll
    for (int rr = 0; rr < 8; ++rr) {
        int row = rr * 32 + (tid >> 3);
        int col = (tid & 7) * 4;
        float4 wf = *(const float4*)(wt + row * WTS + col);
        size_t it = tb + (size_t)(row * NT + col);                 // tile-major
        size_t is = boff + (size_t)row * HWn + sbase + col;        // std (v)
        *(float4*)(w + it) = wf;
        float4 vv4 = *(const float4*)(v + is);
        dp[0] = fmaf(wf.x, vv4.x, dp[0]);
        dp[0] = fmaf(wf.y, vv4.y, dp[0]);
        dp[0] = fmaf(wf.z, vv4.z, dp[0]);
        dp[0] = fmaf(wf.w, vv4.w, dp[0]);
#pragma unroll
        for (int j = 1; j <= K; ++j) {
            ushort4 u = *(const ushort4*)(Qb + (size_t)(j - 1) * NTOT + it);
            dp[j] = fmaf(wf.x, b2f(u.x), dp[j]);
            dp[j] = fmaf(wf.y, b2f(u.y), dp[j]);
            dp[j] = fmaf(wf.z, b2f(u.z), dp[j]);
            dp[j] = fmaf(wf.w, b2f(u.w), dp[j]);
        }
    }
#pragma unroll
    for (int j = 0; j <= K; ++j) {
        float q2 = dp[j];
        for (int off2 = 32; off2 > 0; off2 >>= 1) q2 += __shfl_down(q2, off2);
        if (lane == 0) dred[wvi][j] = q2;
    }
    __syncthreads();
    if (tid <= K)
        atomicAdd(&acc[(K * 8 + tid) * 8 + b],
                  dred[0][tid] + dred[1][tid] + dred[2][tid] + dred[3][tid]);
}

// ---------------- expm of 9x9 per batch (fp64); emits combine coeffs ----------
__global__ __launch_bounds__(128) void expm_kernel(const float* __restrict__ acc,
                                                   float* __restrict__ coordsOut) {
    __shared__ double Am[81], Pm[81], Tm[81];
    __shared__ double ssc;
    __shared__ int sn;
    const int b = blockIdx.x;
    const int t = threadIdx.x;
    const int r = t / 9, c = t % 9;
    double m[8];
    m[0] = sqrt((double)acc[512 + b]);
    for (int j = 1; j < 8; ++j) m[j] = sqrt((double)acc[512 + j * 8 + b]) + 1e-12 * m[j - 1];
    if (t < 81) {
        double val = 0.0;
        if (r < 8 && c < 8) {
            if (r <= c) val = TEND * (double)acc[(c * 8 + r) * 8 + b] / (m[r] * m[c]);
            else if (r == c + 1) val = TEND * sqrt((double)acc[512 + r * 8 + b]) / m[c];
        }
        if (r == 0 && c == 8) val = TEND;
        Am[t] = val;
    }
    __syncthreads();
    if (t == 0) {
        double mx = 0.0;
        for (int rr = 0; rr < 9; ++rr) {
            double s = 0.0;
            for (int cc = 0; cc < 9; ++cc) s += fabs(Am[rr * 9 + cc]);
            if (s > mx) mx = s;
        }
        int n = 0;
        while (mx > 0.25 && n < 48) { mx *= 0.5; ++n; }
        double sc = 1.0;
        for (int ii = 0; ii < n; ++ii) sc *= 0.5;
        sn = n; ssc = sc;
    }
    __syncthreads();
    if (t < 81) Am[t] *= ssc;
    __syncthreads();
    if (t < 81) Pm[t] = (r == c) ? 1.0 : 0.0;
    __syncthreads();
    for (int i = 20; i >= 1; --i) {
        if (t < 81) {
            double s = 0.0;
            for (int k = 0; k < 9; ++k) s += Am[r * 9 + k] * Pm[k * 9 + c];
            Tm[t] = ((r == c) ? 1.0 : 0.0) + s / (double)i;
        }
        __syncthreads();
        if (t < 81) Pm[t] = Tm[t];
        __syncthreads();
    }
    int n = sn;
    for (int q = 0; q < n; ++q) {
        if (t < 81) {
            double s = 0.0;
            for (int k = 0; k < 9; ++k) s += Pm[r * 9 + k] * Pm[k * 9 + c];
            Tm[t] = s;
        }
        __syncthreads();
        if (t < 81) Pm[t] = Tm[t];
        __syncthreads();
    }
    if (t < 8) coordsOut[b * 8 + t] = (float)(Pm[t * 9 + 8] * m[0] / m[t]);
}

// ------ out = coeff_0*v + sum_{j=1..7} coeff_j * U_j (tile-major bf16 Q) ------
__global__ __launch_bounds__(256) void combine_kernel(const unsigned short* __restrict__ Qb,
                                                      const float* __restrict__ v,
                                                      const float* __restrict__ coords,
                                                      float* __restrict__ out) {
    int t = blockIdx.x, b = blockIdx.y;
    const size_t boff = (size_t)b * FB;
    const size_t tb = ((size_t)b * TPB + t) * TSZ;
    float cf[8];
#pragma unroll
    for (int j = 0; j < 8; ++j) cf[j] = coords[b * 8 + j];
    int rg = threadIdx.x >> 3;
    int pos4 = (threadIdx.x & 7) * 4;
#pragma unroll
    for (int ri = 0; ri < 8; ++ri) {
        int r = ri * 32 + rg;
        size_t it = tb + (size_t)(r * NT + pos4);
        size_t is = boff + (size_t)r * HWn + t * NT + pos4;
        float4 vv = *(const float4*)(v + is);
        float a[4] = {cf[0] * vv.x, cf[0] * vv.y, cf[0] * vv.z, cf[0] * vv.w};
#pragma unroll
        for (int j = 1; j < 8; ++j) {
            ushort4 u = *(const ushort4*)(Qb + (size_t)(j - 1) * NTOT + it);
            a[0] = fmaf(cf[j], b2f(u.x), a[0]);
            a[1] = fmaf(cf[j], b2f(u.y), a[1]);
            a[2] = fmaf(cf[j], b2f(u.z), a[2]);
            a[3] = fmaf(cf[j], b2f(u.w), a[3]);
        }
        float4 o = {a[0], a[1], a[2], a[3]};
        *(float4*)(out + is) = o;
    }
}

extern "C" void kernel_launch(void* const* d_in, const int* in_sizes, int n_in,
                              void* d_out, int out_size, void* d_ws, size_t ws_size,
                              hipStream_t stream) {
    const float* s0 = (const float*)d_in[0];
    const float* v  = (const float*)d_in[1];
    const float* W  = (const float*)d_in[2];
    float* out = (float*)d_out;

    // ws (floats): [acc 576 | coords 64 | pad->1024 | Whs 32768 | Wls 32768 |
    //               Qb bf16 7*NTOT]
    float* ws     = (float*)d_ws;
    float* acc    = ws;
    float* coords = ws + 576;
    unsigned short* Whs = (unsigned short*)(ws + 1024);
    unsigned short* Wls = Whs + 65536;
    unsigned short* Qb  = (unsigned short*)(ws + 1024 + 65536);  // 7 bf16 fields, tile-major
    float* w      = out;   // working A-output (fp32, tile-major during steps)

    init_kernel<<<dim3(1), dim3(256), 0, stream>>>(ws);
    wsplit_kernel<<<dim3(8, 16), dim3(64), 0, stream>>>(W, Whs, Wls);

    dim3 ga(TPB, 8), blk(256);
#define STEPK(K) step_kernel<K><<<ga, blk, 0, stream>>>(v, s0, Whs, Wls, Qb, acc, w);
    STEPK(0) STEPK(1) STEPK(2) STEPK(3) STEPK(4) STEPK(5) STEPK(6) STEPK(7)
#undef STEPK

    expm_kernel<<<dim3(8), dim3(128), 0, stream>>>(acc, coords);
    combine_kernel<<<dim3(TPB, 8), blk, 0, stream>>>(Qb, v, coords, out);
}